// Round 5
// baseline (123.058 us; speedup 1.0000x reference)
//
#include <hip/hip_runtime.h>
#include <math.h>

#define KMAX  64
#define LHSZ  64         // local (LDS) hash slots, == wave size
#define GHSZ  256        // global per-batch hash size
#define EMPTY 0xFFFFFFFFu
#define SENT  0xFFFFFFFFu
#define LAM   300.0f
#define MAXNB 256        // max blocks per batch for heavy kernels

struct GTab {            // per-batch global segment table (hash-indexed)
    unsigned key[GHSZ];
    float cnt[GHSZ], s0[GHSZ], s1[GHSZ], s2[GHSZ];
};
struct Ctrl {
    unsigned tk[8];      // per-batch finisher tickets
    unsigned tkF;        // global finisher ticket
    unsigned pad[7];
    float batch_loss[8];
};

__device__ __forceinline__ unsigned key_of(float r, float g, float b) {
    return ((unsigned)r << 16) | ((unsigned)g << 8) | (unsigned)b;
}

// find-or-insert in the 64-entry LDS hash; returns slot. Read-mostly: plain
// volatile probe first, CAS only on EMPTY.
__device__ __forceinline__ int hfi_lds64(unsigned* hkey, unsigned key) {
    unsigned s = (key * 2654435761u) >> 26;   // 6-bit initial slot
    for (int probe = 0; probe < LHSZ; ++probe) {
        unsigned cur = *(volatile unsigned*)&hkey[s];
        if (cur == key) return (int)s;
        if (cur == EMPTY) {
            unsigned old = atomicCAS(&hkey[s], EMPTY, key);
            if (old == EMPTY || old == key) return (int)s;
        } else {
            s = (s + 1) & (LHSZ - 1);
        }
    }
    return (int)(LHSZ - 1);   // table overflow (impossible for K<=64 inputs)
}

__device__ __forceinline__ int hfi_glb(unsigned* gkey, unsigned key) {
    unsigned s = (key * 2654435761u) >> 24;
    while (true) {
        unsigned old = atomicCAS(&gkey[s], EMPTY, key);
        if (old == EMPTY || old == key) return (int)s;
        s = (s + 1) & (GHSZ - 1);
    }
}

__device__ __forceinline__ int lower_bound64(const unsigned* su, unsigned key) {
    int lo = 0;
    if (su[lo + 31] < key) lo += 32;
    if (su[lo + 15] < key) lo += 16;
    if (su[lo + 7]  < key) lo += 8;
    if (su[lo + 3]  < key) lo += 4;
    if (su[lo + 1]  < key) lo += 2;
    if (su[lo]      < key) lo += 1;
    return lo;
}

__device__ __forceinline__ float huber1(float e) {
    float a = fabsf(e);
    return a < 1.0f ? 0.5f * e * e : a - 0.5f;
}

__global__ __launch_bounds__(256) void k_init(GTab* gt, Ctrl* ctrl, int B) {
    int tid = threadIdx.x;
    for (int b = 0; b < B; ++b) {
        GTab* g = &gt[b];
        g->key[tid] = EMPTY;
        g->cnt[tid] = 0.f;
        g->s0[tid] = 0.f; g->s1[tid] = 0.f; g->s2[tid] = 0.f;
    }
    if (tid < 8) ctrl->tk[tid] = 0u;
    if (tid == 0) ctrl->tkF = 0u;
}

// K0: one read of tgt+pred; per-pixel slot find (banked LDS reads only);
// wave broadcast-accumulate into lane-per-slot registers (NO per-pixel
// atomics); block combine via plain LDS; ~48x4 global atomics per block.
__global__ __launch_bounds__(256) void k_accum(const float* __restrict__ pred,
        const float* __restrict__ tgt, GTab* __restrict__ gt, int P, int nb)
{
    int b = blockIdx.y, bx = blockIdx.x, tid = threadIdx.x;
    int lane = tid & 63, w = tid >> 6;
    const float* tg = tgt + (size_t)b * 3 * P;
    const float* pr = pred + (size_t)b * 3 * P;
    GTab* g = &gt[b];

    __shared__ unsigned hkey[LHSZ];
    __shared__ float4 wsum[4][LHSZ];
    if (tid < LHSZ) hkey[tid] = EMPTY;
    __syncthreads();

    float c = 0.f, a0 = 0.f, a1 = 0.f, a2 = 0.f;   // lane-per-slot accumulators

    int ngrp = P >> 2;
    for (int gi = bx * 256 + tid; gi < ngrp; gi += nb * 256) {
        float4 tr = *(const float4*)(tg + 4 * (size_t)gi);
        float4 tc = *(const float4*)(tg + P + 4 * (size_t)gi);
        float4 tb = *(const float4*)(tg + 2 * P + 4 * (size_t)gi);
        float4 pa = *(const float4*)(pr + 4 * (size_t)gi);
        float4 pb = *(const float4*)(pr + P + 4 * (size_t)gi);
        float4 pc = *(const float4*)(pr + 2 * P + 4 * (size_t)gi);
        float t0[4] = {tr.x, tr.y, tr.z, tr.w};
        float t1[4] = {tc.x, tc.y, tc.z, tc.w};
        float t2[4] = {tb.x, tb.y, tb.z, tb.w};
        float q0[4] = {pa.x, pa.y, pa.z, pa.w};
        float q1[4] = {pb.x, pb.y, pb.z, pb.w};
        float q2[4] = {pc.x, pc.y, pc.z, pc.w};
        int sd[4];
        #pragma unroll
        for (int j = 0; j < 4; ++j)
            sd[j] = hfi_lds64(hkey, key_of(t0[j], t1[j], t2[j]));

        // broadcast-accumulate: lane k sums slot k, no atomics
        #pragma unroll
        for (int j = 0; j < 4; ++j) {
            #pragma unroll 16
            for (int r = 0; r < 64; ++r) {
                int s  = __builtin_amdgcn_readlane(sd[j], r);
                int i0 = __builtin_amdgcn_readlane(__float_as_int(q0[j]), r);
                int i1 = __builtin_amdgcn_readlane(__float_as_int(q1[j]), r);
                int i2 = __builtin_amdgcn_readlane(__float_as_int(q2[j]), r);
                bool eq = (lane == s);
                c  += eq ? 1.0f : 0.0f;
                a0 += eq ? __int_as_float(i0) : 0.0f;
                a1 += eq ? __int_as_float(i1) : 0.0f;
                a2 += eq ? __int_as_float(i2) : 0.0f;
            }
        }
    }

    wsum[w][lane] = make_float4(c, a0, a1, a2);
    __syncthreads();

    if (tid < LHSZ) {
        unsigned key = hkey[tid];
        float4 u0 = wsum[0][tid], u1 = wsum[1][tid];
        float4 u2 = wsum[2][tid], u3 = wsum[3][tid];
        float cc = u0.x + u1.x + u2.x + u3.x;
        if (key != EMPTY && cc > 0.f) {
            int gp = hfi_glb(g->key, key);
            atomicAdd(&g->cnt[gp], cc);
            atomicAdd(&g->s0[gp], u0.y + u1.y + u2.y + u3.y);
            atomicAdd(&g->s1[gp], u0.z + u1.z + u2.z + u3.z);
            atomicAdd(&g->s2[gp], u0.w + u1.w + u2.w + u3.w);
        }
    }
}

// K1: per-block derive (compact+sort+constants), P x K main loop, finishers.
__global__ __launch_bounds__(256) void k_main(const float* __restrict__ pred,
        const float* __restrict__ tgt, const GTab* __restrict__ gt,
        float* __restrict__ partial2, Ctrl* __restrict__ ctrl,
        const unsigned char* __restrict__ no_bg, float* __restrict__ out,
        int P, int B, int nb)
{
    int b = blockIdx.y, bx = blockIdx.x, tid = threadIdx.x;
    const float* tg = tgt + (size_t)b * 3 * P;
    const float* pr = pred + (size_t)b * 3 * P;
    const GTab* g = &gt[b];

    __shared__ unsigned ckey[GHSZ];
    __shared__ unsigned cpos[GHSZ];
    __shared__ unsigned su[KMAX];
    __shared__ int spos[KMAX];
    __shared__ float4 smv[KMAX];     // {m0,m1,m2, LAM*a_k}
    __shared__ float4 srv[KMAX];     // {bg-zeroed means, w_h}
    __shared__ int scnted[KMAX];
    __shared__ int sct, sM;
    __shared__ unsigned cc;
    __shared__ double dred[256];
    __shared__ float wred[4];
    __shared__ int amLast;

    // ---- derive segment constants (every block; table is tiny/L2-hot) -----
    if (tid == 0) cc = 0u;
    if (tid < KMAX) su[tid] = SENT;
    __syncthreads();
    {
        unsigned key = g->key[tid];          // kernel boundary = coherent
        if (key != EMPTY) {
            unsigned pos = atomicAdd(&cc, 1u);
            ckey[pos] = key;
            cpos[pos] = (unsigned)tid;
        }
    }
    __syncthreads();
    int C = (int)cc;
    if (tid < C) {
        unsigned key = ckey[tid];
        int rank = 0;
        for (int j = 0; j < C; ++j) rank += (ckey[j] < key) ? 1 : 0;
        if (rank < KMAX) { su[rank] = key; spos[rank] = (int)cpos[tid]; }
    }
    __syncthreads();
    if (tid < KMAX) {
        unsigned key = su[tid];
        bool valid = key != SENT;
        float cnt = 0.f, f0 = 0.f, f1 = 0.f, f2 = 0.f;
        if (valid) {
            int i = spos[tid];
            cnt = g->cnt[i]; f0 = g->s0[i]; f1 = g->s1[i]; f2 = g->s2[i];
        }
        float n = (cnt > 0.f) ? cnt : 1.0f;
        float inv_n = 1.0f / n;
        float m0 = f0 * inv_n, m1 = f1 * inv_n, m2 = f2 * inv_n;
        bool isbg = valid && (key == 0u);
        bool nbg = no_bg[b] != 0;
        bool counted = valid && (cnt > 0.f) && (!isbg || !nbg);
        float n_out = (float)P - cnt;
        bool active = valid && (cnt > 0.f) && !isbg && (n_out > 0.5f);
        float noutf = (n_out > 0.5f) ? n_out : 1.0f;
        float saw = active ? (LAM * 10.0f / (sqrtf(n) * noutf)) : 0.0f;
        float whw = counted ? (1.0f / (3.0f * n)) : 0.0f;
        smv[tid] = make_float4(m0, m1, m2, saw);
        srv[tid] = make_float4(isbg ? 0.f : m0, isbg ? 0.f : m1, isbg ? 0.f : m2, whw);
        scnted[tid] = counted ? 1 : 0;
        unsigned long long mc = __ballot(counted);
        unsigned long long mv = __ballot(valid);
        if (tid == 0) { sct = (int)__popcll(mc); sM = (int)__popcll(mv); }
    }
    __syncthreads();

    // ---- main P x K loop ---------------------------------------------------
    float accs = 0.f;
    const int M2 = sM;
    int ngrp = P >> 2;
    for (int gi = bx * 256 + tid; gi < ngrp; gi += nb * 256) {
        float4 tr = *(const float4*)(tg + 4 * (size_t)gi);
        float4 tc = *(const float4*)(tg + P + 4 * (size_t)gi);
        float4 tb = *(const float4*)(tg + 2 * P + 4 * (size_t)gi);
        float4 pa = *(const float4*)(pr + 4 * (size_t)gi);
        float4 pb = *(const float4*)(pr + P + 4 * (size_t)gi);
        float4 pc = *(const float4*)(pr + 2 * P + 4 * (size_t)gi);
        float t0[4] = {tr.x, tr.y, tr.z, tr.w};
        float t1[4] = {tc.x, tc.y, tc.z, tc.w};
        float t2[4] = {tb.x, tb.y, tb.z, tb.w};
        float q0[4] = {pa.x, pa.y, pa.z, pa.w};
        float q1[4] = {pb.x, pb.y, pb.z, pb.w};
        float q2[4] = {pc.x, pc.y, pc.z, pc.w};
        int sid[4]; float fa[4];
        #pragma unroll
        for (int j = 0; j < 4; ++j) {
            int lo = lower_bound64(su, key_of(t0[j], t1[j], t2[j]));
            sid[j] = lo;
            float4 rv = srv[lo];
            accs += rv.w * (huber1(q0[j] - rv.x) + huber1(q1[j] - rv.y)
                            + huber1(q2[j] - rv.z));
            fa[j] = 0.f;
        }
        for (int k = 0; k < M2; ++k) {
            float4 vv = smv[k];
            #pragma unroll
            for (int j = 0; j < 4; ++j) {
                float e0 = q0[j] - vv.x, e1 = q1[j] - vv.y, e2 = q2[j] - vv.z;
                float d = fmaf(e0, e0, fmaf(e1, e1, e2 * e2));
                fa[j] = fmaf(vv.w, __builtin_amdgcn_rcpf(1.0f + d), fa[j]);
            }
        }
        #pragma unroll
        for (int j = 0; j < 4; ++j) {
            float4 vv = smv[sid[j]];
            float e0 = q0[j] - vv.x, e1 = q1[j] - vv.y, e2 = q2[j] - vv.z;
            float d = fmaf(e0, e0, fmaf(e1, e1, e2 * e2));
            accs += fa[j] - vv.w * __builtin_amdgcn_rcpf(1.0f + d);
        }
    }

    // ---- block reduce + ticket finishers -----------------------------------
    #pragma unroll
    for (int o = 32; o > 0; o >>= 1) accs += __shfl_xor(accs, o);
    int lane = tid & 63, wid = tid >> 6;
    if (lane == 0) wred[wid] = accs;
    __syncthreads();
    if (tid == 0) {
        float tot = wred[0] + wred[1] + wred[2] + wred[3];
        __hip_atomic_store(&partial2[(size_t)b * nb + bx], tot,
                           __ATOMIC_RELEASE, __HIP_MEMORY_SCOPE_AGENT);
        unsigned old = __hip_atomic_fetch_add(&ctrl->tk[b], 1u,
                           __ATOMIC_ACQ_REL, __HIP_MEMORY_SCOPE_AGENT);
        amLast = (old == (unsigned)(nb - 1)) ? 1 : 0;
    }
    __syncthreads();
    if (!amLast) return;

    {
        double dv = 0.0;
        if (tid < nb)
            dv = (double)__hip_atomic_load(&partial2[(size_t)b * nb + tid],
                                           __ATOMIC_ACQUIRE, __HIP_MEMORY_SCOPE_AGENT);
        dred[tid] = dv;
        __syncthreads();
        for (int s = 128; s > 0; s >>= 1) {
            if (tid < s) dred[tid] += dred[tid + s];
            __syncthreads();
        }
    }

    float rs = 0.f;
    if (tid < KMAX && scnted[tid]) {
        float4 a = srv[tid];
        for (int j = 0; j < KMAX; ++j) {
            if (j == tid || !scnted[j]) continue;
            float4 c2 = srv[j];
            float d0 = a.x - c2.x, d1 = a.y - c2.y, d2 = a.z - c2.z;
            rs += LAM / (d0 * d0 + d1 * d1 + d2 * d2 + 1.0f);
        }
    }
    #pragma unroll
    for (int o = 32; o > 0; o >>= 1) rs += __shfl_xor(rs, o);

    if (tid == 0) {
        int ct = sct;
        float ctf = (float)ct;
        float npairs = ctf * (ctf - 1.0f) * 0.5f;
        float mean_sep = (ct > 1) ? (rs * 0.5f / fmaxf(npairs, 1.0f)) : 0.0f;
        float loss = ((float)dred[0] + mean_sep) / fmaxf(ctf, 1.0f);
        __hip_atomic_store(&ctrl->batch_loss[b], loss,
                           __ATOMIC_RELEASE, __HIP_MEMORY_SCOPE_AGENT);
        unsigned old2 = __hip_atomic_fetch_add(&ctrl->tkF, 1u,
                            __ATOMIC_ACQ_REL, __HIP_MEMORY_SCOPE_AGENT);
        if (old2 == (unsigned)(B - 1)) {
            float s = 0.f;
            for (int i = 0; i < B; ++i)
                s += __hip_atomic_load(&ctrl->batch_loss[i],
                                       __ATOMIC_ACQUIRE, __HIP_MEMORY_SCOPE_AGENT);
            out[0] = s / (float)B;
        }
    }
}

extern "C" void kernel_launch(void* const* d_in, const int* in_sizes, int n_in,
                              void* d_out, int out_size, void* d_ws, size_t ws_size,
                              hipStream_t stream) {
    const float* pred = (const float*)d_in[0];
    const float* tgt  = (const float*)d_in[1];
    const unsigned char* nb = (const unsigned char*)d_in[2];
    float* out = (float*)d_out;

    int B = in_sizes[2];
    int P = in_sizes[0] / (3 * B);
    int ngrp = P >> 2;
    int nblk = (ngrp + 255) / 256; if (nblk > MAXNB) nblk = MAXNB;

    char* wsb = (char*)d_ws;
    GTab* gt = (GTab*)wsb;
    size_t gtBytes = (size_t)B * sizeof(GTab);
    Ctrl* ctrl = (Ctrl*)(wsb + ((gtBytes + 255) & ~(size_t)255));
    float* partial2 = (float*)((char*)ctrl + ((sizeof(Ctrl) + 255) & ~(size_t)255));

    k_init <<<1, 256, 0, stream>>>(gt, ctrl, B);
    k_accum<<<dim3(nblk, B), 256, 0, stream>>>(pred, tgt, gt, P, nblk);
    k_main <<<dim3(nblk, B), 256, 0, stream>>>(pred, tgt, gt, partial2, ctrl,
                                               nb, out, P, B, nblk);
}

// Round 6
// 76.478 us; speedup vs baseline: 1.6091x; 1.6091x over previous
//
#include <hip/hip_runtime.h>
#include <math.h>

#define KMAX  64
#define LHSZ  128        // local LDS hash slots (load factor ~0.38 at K=48)
#define GHSZ  256        // global per-batch hash slots
#define EMPTY 0xFFFFFFFFu
#define LAM   300.0f
#define NBA   128        // k_accum blocks per batch
#define NBM   256        // k_main  blocks per batch

struct GTab {            // per-batch global segment table (hash-indexed)
    unsigned key[GHSZ];
    float cnt[GHSZ], s0[GHSZ], s1[GHSZ], s2[GHSZ];
};
struct Ctrl {
    unsigned tk[8];      // per-batch finisher tickets
    unsigned tkF;        // global finisher ticket
    unsigned pad[7];
    float batch_loss[8];
};

__device__ __forceinline__ unsigned key_of(float r, float g, float b) {
    return ((unsigned)r << 16) | ((unsigned)g << 8) | (unsigned)b;
}

__device__ __forceinline__ int hfi_lds(unsigned* hkey, unsigned key) {
    unsigned s = (key * 2654435761u) >> 25;        // 7-bit slot
    for (int p = 0; p < LHSZ; ++p) {
        unsigned cur = *(volatile unsigned*)&hkey[s];
        if (cur == key) return (int)s;
        if (cur == EMPTY) {
            unsigned old = atomicCAS(&hkey[s], EMPTY, key);
            if (old == EMPTY || old == key) return (int)s;
        } else {
            s = (s + 1) & (LHSZ - 1);
        }
    }
    return LHSZ - 1;
}

__device__ __forceinline__ int hfi_glb(unsigned* gkey, unsigned key) {
    unsigned s = (key * 2654435761u) >> 24;
    while (true) {
        unsigned old = atomicCAS(&gkey[s], EMPTY, key);
        if (old == EMPTY || old == key) return (int)s;
        s = (s + 1) & (GHSZ - 1);
    }
}

__device__ __forceinline__ float huber1(float e) {
    float a = fabsf(e);
    return a < 1.0f ? 0.5f * e * e : a - 0.5f;
}

__global__ __launch_bounds__(256) void k_init(GTab* gt, Ctrl* ctrl, int B) {
    int tid = threadIdx.x;
    for (int b = 0; b < B; ++b) {
        GTab* g = &gt[b];
        g->key[tid] = EMPTY;
        g->cnt[tid] = 0.f;
        g->s0[tid] = 0.f; g->s1[tid] = 0.f; g->s2[tid] = 0.f;
    }
    if (tid < 8) ctrl->tk[tid] = 0u;
    if (tid == 0) ctrl->tkF = 0u;
}

// K0: one pass over tgt+pred; LDS hash find-or-insert (~1.3 banked reads) +
// 4 LDS atomicAdds per pixel (i.i.d. slots -> ~2-way conflicts); flush <=48
// slots per block into the per-batch global hash.
__global__ __launch_bounds__(256) void k_accum(const float* __restrict__ pred,
        const float* __restrict__ tgt, GTab* __restrict__ gt, int P, int nb)
{
    int b = blockIdx.y, bx = blockIdx.x, tid = threadIdx.x;
    const float* tg = tgt + (size_t)b * 3 * P;
    const float* pr = pred + (size_t)b * 3 * P;
    GTab* g = &gt[b];

    __shared__ unsigned hkey[LHSZ];
    __shared__ float sc[LHSZ], s0[LHSZ], s1[LHSZ], s2[LHSZ];
    if (tid < LHSZ) {
        hkey[tid] = EMPTY;
        sc[tid] = 0.f; s0[tid] = 0.f; s1[tid] = 0.f; s2[tid] = 0.f;
    }
    __syncthreads();

    int ngrp = P >> 2;
    for (int gi = bx * 256 + tid; gi < ngrp; gi += nb * 256) {
        float4 tr = *(const float4*)(tg + 4 * (size_t)gi);
        float4 tc = *(const float4*)(tg + P + 4 * (size_t)gi);
        float4 tb = *(const float4*)(tg + 2 * P + 4 * (size_t)gi);
        float4 pa = *(const float4*)(pr + 4 * (size_t)gi);
        float4 pb = *(const float4*)(pr + P + 4 * (size_t)gi);
        float4 pc = *(const float4*)(pr + 2 * P + 4 * (size_t)gi);
        float t0[4] = {tr.x, tr.y, tr.z, tr.w};
        float t1[4] = {tc.x, tc.y, tc.z, tc.w};
        float t2[4] = {tb.x, tb.y, tb.z, tb.w};
        float q0[4] = {pa.x, pa.y, pa.z, pa.w};
        float q1[4] = {pb.x, pb.y, pb.z, pb.w};
        float q2[4] = {pc.x, pc.y, pc.z, pc.w};
        #pragma unroll
        for (int j = 0; j < 4; ++j) {
            int s = hfi_lds(hkey, key_of(t0[j], t1[j], t2[j]));
            atomicAdd(&sc[s], 1.0f);
            atomicAdd(&s0[s], q0[j]);
            atomicAdd(&s1[s], q1[j]);
            atomicAdd(&s2[s], q2[j]);
        }
    }
    __syncthreads();

    if (tid < LHSZ) {
        unsigned key = hkey[tid];
        float c = sc[tid];
        if (key != EMPTY && c > 0.f) {
            int gp = hfi_glb(g->key, key);
            atomicAdd(&g->cnt[gp], c);
            atomicAdd(&g->s0[gp], s0[tid]);
            atomicAdd(&g->s1[gp], s1[tid]);
            atomicAdd(&g->s2[gp], s2[tid]);
        }
    }
}

// K1: compact global hash -> dense segments (no sort; loss is permutation-
// invariant), per-pixel ~1 hash probe + map read, P x K loop, finishers.
__global__ __launch_bounds__(256) void k_main(const float* __restrict__ pred,
        const float* __restrict__ tgt, const GTab* __restrict__ gt,
        float* __restrict__ partial2, Ctrl* __restrict__ ctrl,
        const unsigned char* __restrict__ no_bg, float* __restrict__ out,
        int P, int B, int nb)
{
    int b = blockIdx.y, bx = blockIdx.x, tid = threadIdx.x;
    const float* tg = tgt + (size_t)b * 3 * P;
    const float* pr = pred + (size_t)b * 3 * P;
    const GTab* g = &gt[b];

    __shared__ unsigned skey[GHSZ];
    __shared__ unsigned char g2d[GHSZ];
    __shared__ unsigned dkey[KMAX];
    __shared__ float dcnt[KMAX];
    __shared__ float dsx[KMAX], dsy[KMAX], dsz[KMAX];
    __shared__ float4 smv[KMAX];     // {m0,m1,m2, LAM*a_k}
    __shared__ float4 srv[KMAX];     // {bg-zeroed means, w_h}
    __shared__ int scnted[KMAX];
    __shared__ unsigned cc;
    __shared__ int sct, sC;
    __shared__ double dred[256];
    __shared__ float wred[4];
    __shared__ int amLast;

    if (tid == 0) cc = 0u;
    __syncthreads();
    {
        unsigned key = g->key[tid];              // kernel boundary = coherent
        skey[tid] = key;
        g2d[tid] = 0;
        if (key != EMPTY) {
            unsigned d = atomicAdd(&cc, 1u);
            if (d < KMAX) {
                g2d[tid] = (unsigned char)d;
                dkey[d] = key;
                dcnt[d] = g->cnt[tid];
                dsx[d] = g->s0[tid]; dsy[d] = g->s1[tid]; dsz[d] = g->s2[tid];
            }
        }
    }
    __syncthreads();
    if (tid < KMAX) {
        int C = (int)cc; if (C > KMAX) C = KMAX;
        bool valid = tid < C;
        unsigned key = valid ? dkey[tid] : 0xFFFFFFFEu;
        float cnt = valid ? dcnt[tid] : 0.f;
        float n = (cnt > 0.f) ? cnt : 1.0f;
        float inv_n = 1.0f / n;
        float m0 = valid ? dsx[tid] * inv_n : 0.f;
        float m1 = valid ? dsy[tid] * inv_n : 0.f;
        float m2 = valid ? dsz[tid] * inv_n : 0.f;
        bool isbg = valid && (key == 0u);
        bool nbg = no_bg[b] != 0;
        bool counted = valid && (cnt > 0.f) && (!isbg || !nbg);
        float n_out = (float)P - cnt;
        bool active = valid && (cnt > 0.f) && !isbg && (n_out > 0.5f);
        float noutf = (n_out > 0.5f) ? n_out : 1.0f;
        float saw = active ? (LAM * 10.0f / (sqrtf(n) * noutf)) : 0.0f;
        float whw = counted ? (1.0f / (3.0f * n)) : 0.0f;
        smv[tid] = make_float4(m0, m1, m2, saw);
        srv[tid] = make_float4(isbg ? 0.f : m0, isbg ? 0.f : m1, isbg ? 0.f : m2, whw);
        scnted[tid] = counted ? 1 : 0;
        unsigned long long mc = __ballot(counted);
        if (tid == 0) { sct = (int)__popcll(mc); sC = C; }
    }
    __syncthreads();

    // ---- main P x K loop ---------------------------------------------------
    float accs = 0.f;
    const int M2 = sC;
    int ngrp = P >> 2;
    for (int gi = bx * 256 + tid; gi < ngrp; gi += nb * 256) {
        float4 tr = *(const float4*)(tg + 4 * (size_t)gi);
        float4 tc = *(const float4*)(tg + P + 4 * (size_t)gi);
        float4 tb = *(const float4*)(tg + 2 * P + 4 * (size_t)gi);
        float4 pa = *(const float4*)(pr + 4 * (size_t)gi);
        float4 pb = *(const float4*)(pr + P + 4 * (size_t)gi);
        float4 pc = *(const float4*)(pr + 2 * P + 4 * (size_t)gi);
        float t0[4] = {tr.x, tr.y, tr.z, tr.w};
        float t1[4] = {tc.x, tc.y, tc.z, tc.w};
        float t2[4] = {tb.x, tb.y, tb.z, tb.w};
        float q0[4] = {pa.x, pa.y, pa.z, pa.w};
        float q1[4] = {pb.x, pb.y, pb.z, pb.w};
        float q2[4] = {pc.x, pc.y, pc.z, pc.w};
        int sid[4]; float fa[4];
        #pragma unroll
        for (int j = 0; j < 4; ++j) {
            unsigned key = key_of(t0[j], t1[j], t2[j]);
            unsigned s = (key * 2654435761u) >> 24;
            for (int p = 0; p < GHSZ; ++p) {
                if (skey[s] == key) break;
                s = (s + 1) & (GHSZ - 1);
            }
            int d = g2d[s];
            sid[j] = d;
            float4 rv = srv[d];
            accs += rv.w * (huber1(q0[j] - rv.x) + huber1(q1[j] - rv.y)
                            + huber1(q2[j] - rv.z));
            fa[j] = 0.f;
        }
        for (int k = 0; k < M2; ++k) {
            float4 vv = smv[k];
            #pragma unroll
            for (int j = 0; j < 4; ++j) {
                float e0 = q0[j] - vv.x, e1 = q1[j] - vv.y, e2 = q2[j] - vv.z;
                float d = fmaf(e0, e0, fmaf(e1, e1, e2 * e2));
                fa[j] = fmaf(vv.w, __builtin_amdgcn_rcpf(1.0f + d), fa[j]);
            }
        }
        #pragma unroll
        for (int j = 0; j < 4; ++j) {
            float4 vv = smv[sid[j]];
            float e0 = q0[j] - vv.x, e1 = q1[j] - vv.y, e2 = q2[j] - vv.z;
            float d = fmaf(e0, e0, fmaf(e1, e1, e2 * e2));
            accs += fa[j] - vv.w * __builtin_amdgcn_rcpf(1.0f + d);
        }
    }

    // ---- block reduce + ticket finishers -----------------------------------
    #pragma unroll
    for (int o = 32; o > 0; o >>= 1) accs += __shfl_xor(accs, o);
    int lane = tid & 63, wid = tid >> 6;
    if (lane == 0) wred[wid] = accs;
    __syncthreads();
    if (tid == 0) {
        float tot = wred[0] + wred[1] + wred[2] + wred[3];
        __hip_atomic_store(&partial2[(size_t)b * nb + bx], tot,
                           __ATOMIC_RELEASE, __HIP_MEMORY_SCOPE_AGENT);
        unsigned old = __hip_atomic_fetch_add(&ctrl->tk[b], 1u,
                           __ATOMIC_ACQ_REL, __HIP_MEMORY_SCOPE_AGENT);
        amLast = (old == (unsigned)(nb - 1)) ? 1 : 0;
    }
    __syncthreads();
    if (!amLast) return;

    {
        double dv = 0.0;
        if (tid < nb)
            dv = (double)__hip_atomic_load(&partial2[(size_t)b * nb + tid],
                                           __ATOMIC_ACQUIRE, __HIP_MEMORY_SCOPE_AGENT);
        dred[tid] = dv;
        __syncthreads();
        for (int s = 128; s > 0; s >>= 1) {
            if (tid < s) dred[tid] += dred[tid + s];
            __syncthreads();
        }
    }

    float rs = 0.f;
    if (tid < KMAX && scnted[tid]) {
        float4 a = srv[tid];
        int C = sC;
        for (int j = 0; j < C; ++j) {
            if (j == tid || !scnted[j]) continue;
            float4 c2 = srv[j];
            float d0 = a.x - c2.x, d1 = a.y - c2.y, d2 = a.z - c2.z;
            rs += LAM / (d0 * d0 + d1 * d1 + d2 * d2 + 1.0f);
        }
    }
    #pragma unroll
    for (int o = 32; o > 0; o >>= 1) rs += __shfl_xor(rs, o);

    if (tid == 0) {
        int ct = sct;
        float ctf = (float)ct;
        float npairs = ctf * (ctf - 1.0f) * 0.5f;
        float mean_sep = (ct > 1) ? (rs * 0.5f / fmaxf(npairs, 1.0f)) : 0.0f;
        float loss = ((float)dred[0] + mean_sep) / fmaxf(ctf, 1.0f);
        __hip_atomic_store(&ctrl->batch_loss[b], loss,
                           __ATOMIC_RELEASE, __HIP_MEMORY_SCOPE_AGENT);
        unsigned old2 = __hip_atomic_fetch_add(&ctrl->tkF, 1u,
                            __ATOMIC_ACQ_REL, __HIP_MEMORY_SCOPE_AGENT);
        if (old2 == (unsigned)(B - 1)) {
            float s = 0.f;
            for (int i = 0; i < B; ++i)
                s += __hip_atomic_load(&ctrl->batch_loss[i],
                                       __ATOMIC_ACQUIRE, __HIP_MEMORY_SCOPE_AGENT);
            out[0] = s / (float)B;
        }
    }
}

extern "C" void kernel_launch(void* const* d_in, const int* in_sizes, int n_in,
                              void* d_out, int out_size, void* d_ws, size_t ws_size,
                              hipStream_t stream) {
    const float* pred = (const float*)d_in[0];
    const float* tgt  = (const float*)d_in[1];
    const unsigned char* nb = (const unsigned char*)d_in[2];
    float* out = (float*)d_out;

    int B = in_sizes[2];
    int P = in_sizes[0] / (3 * B);
    int ngrp = P >> 2;
    int nba = (ngrp + 255) / 256; if (nba > NBA) nba = NBA;
    int nbm = (ngrp + 255) / 256; if (nbm > NBM) nbm = NBM;

    char* wsb = (char*)d_ws;
    GTab* gt = (GTab*)wsb;
    size_t gtBytes = (size_t)B * sizeof(GTab);
    Ctrl* ctrl = (Ctrl*)(wsb + ((gtBytes + 255) & ~(size_t)255));
    float* partial2 = (float*)((char*)ctrl + ((sizeof(Ctrl) + 255) & ~(size_t)255));

    k_init <<<1, 256, 0, stream>>>(gt, ctrl, B);
    k_accum<<<dim3(nba, B), 256, 0, stream>>>(pred, tgt, gt, P, nba);
    k_main <<<dim3(nbm, B), 256, 0, stream>>>(pred, tgt, gt, partial2, ctrl,
                                              nb, out, P, B, nbm);
}